// Round 31
// baseline (58.664 us; speedup 1.0000x reference)
//
#include <hip/hip_runtime.h>
#include <hip/hip_bf16.h>

#define SCOPE 63
#define BT 256
#define RPT 64                      // rows per tile
#define TPB 4                       // tiles per block
#define TILE_B 16384                // 64 rows x 256 B (padded [64][64] fp32)

typedef __attribute__((ext_vector_type(8))) __bf16 v8bf;
typedef __attribute__((ext_vector_type(4))) float f32x4;

#define GLL(gp, lp) __builtin_amdgcn_global_load_lds(                         \
    (const __attribute__((address_space(1))) void*)(gp),                      \
    (__attribute__((address_space(3))) void*)(lp), 16, 0, 0)

// ws layout: [0,256) g float[63]; [256,8448) Bhi bf16[4096]; [8448,16640) Blo
#define WS_BHI_OFF 256
#define WS_BLO_OFF 8448

// ---------------------------------------------------------------------------
// Kernel 1 (one-time, ~2us): g = IFFT(1/FFT(delta-f)) in fp64 via 63-entry
// twiddle table + fragment-ordered bf16 hi/lo B arrays into d_ws.
// ---------------------------------------------------------------------------
__global__ void compute_inverse_filter(const float* __restrict__ f,
                                       float* __restrict__ ws) {
    __shared__ double cd[SCOPE];
    __shared__ double sd[SCOPE];
    __shared__ double hre[SCOPE];
    __shared__ double him[SCOPE];
    __shared__ float gsm[SCOPE];
    const double TWO_PI = 6.283185307179586476925286766559;
    int t = threadIdx.x;

    if (t < SCOPE) {
        double ang = -TWO_PI * (double)t / (double)SCOPE;
        cd[t] = cos(ang);
        sd[t] = sin(ang);
    }
    __syncthreads();

    if (t < SCOPE) {
        double re = 0.0, im = 0.0;
        for (int n = 0; n < SCOPE; ++n) {
            double x = (n == 0 ? 1.0 : 0.0) - (double)f[n];
            int m = (t * n) % SCOPE;
            re += x * cd[m];
            im += x * sd[m];
        }
        double d = re * re + im * im;
        hre[t] = re / d;
        him[t] = -im / d;
    }
    __syncthreads();

    if (t < SCOPE) {
        double acc = 0.0;
        for (int k = 0; k < SCOPE; ++k) {
            int m = (k * t) % SCOPE;
            acc += hre[k] * cd[m] + him[k] * sd[m];
        }
        float gv = (float)(acc / (double)SCOPE);
        ws[t] = gv;
        gsm[t] = gv;
    }
    __syncthreads();

    __bf16* Bhi = (__bf16*)((char*)ws + WS_BHI_OFF);
    __bf16* Blo = (__bf16*)((char*)ws + WS_BLO_OFF);
    for (int fidx = t; fidx < 4096; fidx += blockDim.x) {
        const int j  = fidx & 7;
        const int fl = (fidx >> 3) & 63;
        const int kt = (fidx >> 9) & 1;
        const int nt = fidx >> 10;
        const int k  = 8 * (fl >> 4) + j + 32 * kt;
        const int n  = 16 * nt + (fl & 15);
        float v = (k < SCOPE && n < SCOPE) ? gsm[(n - k + SCOPE) % SCOPE] : 0.0f;
        __bf16 h = (__bf16)v;
        Bhi[fidx] = h;
        Blo[fidx] = (__bf16)(v - (float)h);
    }
}

// ---------------------------------------------------------------------------
// Stage one 64-row tile: swizzled per-lane SOURCE -> linear LDS dest (GLL).
// Slot (r,gl) holds float group gk = gl ^ (r&7) of row r.
// ---------------------------------------------------------------------------
__device__ __forceinline__ void stage_tile(const float* __restrict__ srcRows,
                                           unsigned char* buf, int tid,
                                           bool lastTile) {
#pragma unroll
    for (int it = 0; it < 4; ++it) {
        const int i  = it * 256 + tid;   // LDS 16B-group index
        const int r  = i >> 4;
        const int gl = i & 15;
        const int gk = gl ^ (r & 7);
        const bool oob = lastTile && (r == 63) && (gk == 15);
        if (!oob)
            GLL(srcRows + r * SCOPE + 4 * gk, buf + i * 16);
    }
    if (lastTile && tid < 4) {          // r=63,gk=15: floats 60..62 + zero pad
        const int r = 63, gl = 15 ^ 7;
        float v = (tid < 3) ? srcRows[r * SCOPE + 60 + tid] : 0.0f;
        *(float*)(buf + r * 256 + gl * 16 + tid * 4) = v;
    }
}

// ---------------------------------------------------------------------------
// Compute one tile from buf and store it (wave-local C region; no barrier).
// ---------------------------------------------------------------------------
__device__ __forceinline__ void compute_store(unsigned char* buf,
                                              float* __restrict__ dstRows,
                                              int w, int l, int c, int q,
                                              const v8bf (&bh)[4][2],
                                              const v8bf (&bl)[4][2]) {
    const int r  = 16 * w + c;
    const int rx = r & 7;
    v8bf ah[2], al[2];
#pragma unroll
    for (int kt = 0; kt < 2; ++kt) {
        const int fg0 = 8 * kt + 2 * q;
        float4 v0 = *(const float4*)(buf + r * 256 + ((fg0 ^ rx) << 4));
        float4 v1 = *(const float4*)(buf + r * 256 + (((fg0 + 1) ^ rx) << 4));
        float tmp[8] = {v0.x, v0.y, v0.z, v0.w, v1.x, v1.y, v1.z, v1.w};
#pragma unroll
        for (int j = 0; j < 8; ++j) {
            float v = tmp[j];
            __bf16 h = (__bf16)v;
            ah[kt][j] = h;
            al[kt][j] = (__bf16)(v - (float)h);
        }
    }

    float* cw = (float*)(buf + w * 4096);   // wave region: 16 rows x 63 fp32
#pragma unroll
    for (int nt = 0; nt < 4; ++nt) {
        f32x4 acc = {0.f, 0.f, 0.f, 0.f};
#pragma unroll
        for (int kt = 0; kt < 2; ++kt) {
            acc = __builtin_amdgcn_mfma_f32_16x16x32_bf16(ah[kt], bh[nt][kt], acc, 0, 0, 0);
            acc = __builtin_amdgcn_mfma_f32_16x16x32_bf16(ah[kt], bl[nt][kt], acc, 0, 0, 0);
            acc = __builtin_amdgcn_mfma_f32_16x16x32_bf16(al[kt], bh[nt][kt], acc, 0, 0, 0);
        }
        const int col = 16 * nt + c;
        if (col < SCOPE) {
            float* cp = cw + (4 * q) * SCOPE + col;
#pragma unroll
            for (int i = 0; i < 4; ++i)
                cp[i * SCOPE] = acc[i];
        }
    }

    // per-wave store of own 16 rows (wave-local DS ordering; no barrier)
    float* wdst = dstRows + (long long)w * (16 * SCOPE);
#pragma unroll
    for (int it = 0; it < 4; ++it) {
        const int gidx = it * 64 + l;
        if (gidx < 252) {
            float4 v = *(const float4*)(buf + w * 4096 + gidx * 16);
            *(float4*)(wdst + gidx * 4) = v;
        }
    }
}

// ---------------------------------------------------------------------------
// Kernel 2, r31: 2-deep GLL double-buffer pipeline, 4 tiles/block, 1 barrier
// per tile. stage(t+1) is ISSUED before compute(t): GLL has no dest register
// so the compiler cannot sink it (unlike r22's reg-prefetch) — tile t+1's HBM
// latency hides under compute+store(t). Static bufA/bufB (rule #20).
// LDS 2x16.4 KB = 33 KB -> 4 blocks/CU (16 waves). B-frags from global ws.
// ---------------------------------------------------------------------------
__global__ void __launch_bounds__(BT)
circ_conv_kernel(const float* __restrict__ A,
                 const float* __restrict__ WS,
                 float* __restrict__ O) {
    __shared__ __align__(16) unsigned char bufA[TILE_B + 16];
    __shared__ __align__(16) unsigned char bufB[TILE_B + 16];

    const int tid = threadIdx.x;
    const int w   = tid >> 6;
    const int l   = tid & 63;
    const int c   = l & 15;
    const int q   = l >> 4;

    const long long tile0 = (long long)blockIdx.x * TPB;
    const long long lastT = (long long)gridDim.x * TPB - 1;

    // B fragments: global ws, L2 broadcast (identical across blocks)
    const v8bf* BH = (const v8bf*)((const char*)WS + WS_BHI_OFF);
    const v8bf* BL = (const v8bf*)((const char*)WS + WS_BLO_OFF);
    v8bf bh[4][2], bl[4][2];
#pragma unroll
    for (int nt = 0; nt < 4; ++nt)
#pragma unroll
        for (int kt = 0; kt < 2; ++kt) {
            bh[nt][kt] = BH[(nt * 2 + kt) * 64 + l];
            bl[nt][kt] = BL[(nt * 2 + kt) * 64 + l];
        }

#define SRC(tt) (A + (tile0 + (tt)) * (long long)(RPT * SCOPE))
#define DST(tt) (O + (tile0 + (tt)) * (long long)(RPT * SCOPE))
#define ISLAST(tt) (tile0 + (tt) == lastT)

    stage_tile(SRC(0), bufA, tid, ISLAST(0));
    __syncthreads();                                  // tile0 ready

    stage_tile(SRC(1), bufB, tid, ISLAST(1));         // in flight under t0
    compute_store(bufA, DST(0), w, l, c, q, bh, bl);
    __syncthreads();                                  // tile1 ready, bufA free

    stage_tile(SRC(2), bufA, tid, ISLAST(2));
    compute_store(bufB, DST(1), w, l, c, q, bh, bl);
    __syncthreads();                                  // tile2 ready, bufB free

    stage_tile(SRC(3), bufB, tid, ISLAST(3));
    compute_store(bufA, DST(2), w, l, c, q, bh, bl);
    __syncthreads();                                  // tile3 ready

    compute_store(bufB, DST(3), w, l, c, q, bh, bl);

#undef SRC
#undef DST
#undef ISLAST
}

// ---------------------------------------------------------------------------
extern "C" void kernel_launch(void* const* d_in, const int* in_sizes, int n_in,
                              void* d_out, int out_size, void* d_ws, size_t ws_size,
                              hipStream_t stream) {
    const float* activations = (const float*)d_in[0];
    const float* filt        = (const float*)d_in[1];
    float* out               = (float*)d_out;
    float* ws                = (float*)d_ws;   // g + B-fragment arrays (~17 KB)

    hipLaunchKernelGGL(compute_inverse_filter, dim3(1), dim3(BT), 0, stream,
                       filt, ws);

    const long long total = (long long)in_sizes[0];
    const long long rows  = total / SCOPE;               // 524288
    const long long tiles = rows / RPT;                  // 8192
    const int blocks      = (int)(tiles / TPB);          // 2048, exact

    hipLaunchKernelGGL(circ_conv_kernel, dim3(blocks), dim3(BT), 0,
                       stream, activations, ws, out);
}

// Round 32
// 58.352 us; speedup vs baseline: 1.0053x; 1.0053x over previous
//
#include <hip/hip_runtime.h>
#include <hip/hip_bf16.h>

#define SCOPE 63
#define BT 256
#define RPB 64                      // rows per block (16 per wave)

typedef __attribute__((ext_vector_type(8))) __bf16 v8bf;
typedef __attribute__((ext_vector_type(4))) float f32x4;

#define GLL(gp, lp) __builtin_amdgcn_global_load_lds(                         \
    (const __attribute__((address_space(1))) void*)(gp),                      \
    (__attribute__((address_space(3))) void*)(lp), 16, 0, 0)

// ws layout: [0,256) g float[63]; [256,8448) Bhi bf16[4096]; [8448,16640) Blo
#define WS_BHI_OFF 256
#define WS_BLO_OFF 8448

// ---------------------------------------------------------------------------
// Kernel 1 (one-time, ~2us): g = IFFT(1/FFT(delta-f)) in fp64 via 63-entry
// twiddle table + fragment-ordered bf16 hi/lo B arrays into d_ws.
// ---------------------------------------------------------------------------
__global__ void compute_inverse_filter(const float* __restrict__ f,
                                       float* __restrict__ ws) {
    __shared__ double cd[SCOPE];
    __shared__ double sd[SCOPE];
    __shared__ double hre[SCOPE];
    __shared__ double him[SCOPE];
    __shared__ float gsm[SCOPE];
    const double TWO_PI = 6.283185307179586476925286766559;
    int t = threadIdx.x;

    if (t < SCOPE) {
        double ang = -TWO_PI * (double)t / (double)SCOPE;
        cd[t] = cos(ang);
        sd[t] = sin(ang);
    }
    __syncthreads();

    if (t < SCOPE) {
        double re = 0.0, im = 0.0;
        for (int n = 0; n < SCOPE; ++n) {
            double x = (n == 0 ? 1.0 : 0.0) - (double)f[n];
            int m = (t * n) % SCOPE;
            re += x * cd[m];
            im += x * sd[m];
        }
        double d = re * re + im * im;
        hre[t] = re / d;
        him[t] = -im / d;
    }
    __syncthreads();

    if (t < SCOPE) {
        double acc = 0.0;
        for (int k = 0; k < SCOPE; ++k) {
            int m = (k * t) % SCOPE;
            acc += hre[k] * cd[m] + him[k] * sd[m];
        }
        float gv = (float)(acc / (double)SCOPE);
        ws[t] = gv;
        gsm[t] = gv;
    }
    __syncthreads();

    __bf16* Bhi = (__bf16*)((char*)ws + WS_BHI_OFF);
    __bf16* Blo = (__bf16*)((char*)ws + WS_BLO_OFF);
    for (int fidx = t; fidx < 4096; fidx += blockDim.x) {
        const int j  = fidx & 7;
        const int fl = (fidx >> 3) & 63;
        const int kt = (fidx >> 9) & 1;
        const int nt = fidx >> 10;
        const int k  = 8 * (fl >> 4) + j + 32 * kt;
        const int n  = 16 * nt + (fl & 15);
        float v = (k < SCOPE && n < SCOPE) ? gsm[(n - k + SCOPE) % SCOPE] : 0.0f;
        __bf16 h = (__bf16)v;
        Bhi[fidx] = h;
        Blo[fidx] = (__bf16)(v - (float)h);
    }
}

// ---------------------------------------------------------------------------
// Kernel 2, r32: BARRIER-FREE wave-independent pipeline.
//
// Insight: in the r30 structure waves never share data — wave w computes,
// stores, and (now) STAGES only rows 16w..16w+15. All __syncthreads deleted;
// the only wait is a WAVE-LOCAL s_waitcnt vmcnt(0) after the wave's own 256
// GLLs. 16 resident waves/CU each run stage->wait->compute->store at
// independent phases, so HBM stays busy (fillBuffer-style TLP) instead of
// lockstep stage/drain (r15-r31: all 54-58 us).
//
// LDS [64][64] fp32, slot (r,gl) = float group gk = gl^(r&7) of row r
// (r&7 == rr&7 since r = 16w + rr). A-frag reads: aligned swizzled b128.
// C overwrites the wave's own region compactly; per-wave linear store.
// ---------------------------------------------------------------------------
__global__ void __launch_bounds__(BT)
circ_conv_kernel(const float* __restrict__ A,
                 const float* __restrict__ WS,
                 float* __restrict__ O) {
    __shared__ __align__(16) unsigned char tile[16384 + 16];

    const int tid = threadIdx.x;
    const int w   = tid >> 6;        // wave in block
    const int l   = tid & 63;        // lane in wave
    const int c   = l & 15;          // fragment column index
    const int q   = l >> 4;          // fragment k-group / row-group

    const long long row0 = (long long)blockIdx.x * RPB;
    const float* __restrict__ src = A + row0 * SCOPE;
    float* __restrict__ dst       = O + row0 * SCOPE;
    const bool last = ((int)blockIdx.x == (int)gridDim.x - 1);

    unsigned char* wbuf = tile + w * 4096;   // wave's 16 rows x 256 B

    // ---- wave-local staging: wave w stages its own rows 16w..16w+15 ----
#pragma unroll
    for (int it = 0; it < 4; ++it) {
        const int gi = it * 64 + l;          // group in wave region: 0..255
        const int rr = gi >> 4;              // row within wave's 16
        const int gl = gi & 15;
        const int gk = gl ^ (rr & 7);        // swizzled source float group
        const int gr = 16 * w + rr;          // global row in tile
        const bool oob = last && (gr == 63) && (gk == 15);
        if (!oob)
            GLL(src + gr * SCOPE + 4 * gk, wbuf + gi * 16);
    }
    // last-block fallback (row 63, gk=15 -> gl = 15^7 = 8): wave 3 handles it
    if (last && w == 3 && l < 4) {
        float v = (l < 3) ? src[63 * SCOPE + 60 + l] : 0.0f;
        *(float*)(tile + 63 * 256 + 8 * 16 + l * 4) = v;
    }

    // ---- B fragments: global ws, L2 broadcast (independent of staging) ----
    const v8bf* BH = (const v8bf*)((const char*)WS + WS_BHI_OFF);
    const v8bf* BL = (const v8bf*)((const char*)WS + WS_BLO_OFF);
    v8bf bh[4][2], bl[4][2];
#pragma unroll
    for (int nt = 0; nt < 4; ++nt)
#pragma unroll
        for (int kt = 0; kt < 2; ++kt) {
            bh[nt][kt] = BH[(nt * 2 + kt) * 64 + l];
            bl[nt][kt] = BL[(nt * 2 + kt) * 64 + l];
        }

    // ---- wave-local wait: this wave's GLLs (and ds_write fallback) done ----
    asm volatile("s_waitcnt vmcnt(0) lgkmcnt(0)" ::: "memory");
    __builtin_amdgcn_sched_barrier(0);   // rule #18: pin ds_reads behind wait

    // ---- A fragments: aligned swizzled b128 pairs from own rows ----
    const int r  = 16 * w + c;
    const int rx = r & 7;
    v8bf ah[2], al[2];
#pragma unroll
    for (int kt = 0; kt < 2; ++kt) {
        const int fg0 = 8 * kt + 2 * q;
        float4 v0 = *(const float4*)(tile + r * 256 + ((fg0 ^ rx) << 4));
        float4 v1 = *(const float4*)(tile + r * 256 + (((fg0 + 1) ^ rx) << 4));
        float tmp[8] = {v0.x, v0.y, v0.z, v0.w, v1.x, v1.y, v1.z, v1.w};
#pragma unroll
        for (int j = 0; j < 8; ++j) {
            float v = tmp[j];
            __bf16 h = (__bf16)v;
            ah[kt][j] = h;
            al[kt][j] = (__bf16)(v - (float)h);
        }
    }

    // ---- 24 MFMA; C compact into own region (overwrites own A rows) ----
    float* cw = (float*)wbuf;            // 16 rows x 63 fp32 compact
#pragma unroll
    for (int nt = 0; nt < 4; ++nt) {
        f32x4 acc = {0.f, 0.f, 0.f, 0.f};
#pragma unroll
        for (int kt = 0; kt < 2; ++kt) {
            acc = __builtin_amdgcn_mfma_f32_16x16x32_bf16(ah[kt], bh[nt][kt], acc, 0, 0, 0);
            acc = __builtin_amdgcn_mfma_f32_16x16x32_bf16(ah[kt], bl[nt][kt], acc, 0, 0, 0);
            acc = __builtin_amdgcn_mfma_f32_16x16x32_bf16(al[kt], bh[nt][kt], acc, 0, 0, 0);
        }
        const int col = 16 * nt + c;
        if (col < SCOPE) {
            float* cp = cw + (4 * q) * SCOPE + col;   // rows rr = 4q + i
#pragma unroll
            for (int i = 0; i < 4; ++i)
                cp[i * SCOPE] = acc[i];
        }
    }

    // ---- per-wave store of own 16 rows (wave-local DS ordering) ----
    float* wdst = dst + (long long)w * (16 * SCOPE);
#pragma unroll
    for (int it = 0; it < 4; ++it) {
        const int gidx = it * 64 + l;
        if (gidx < 252) {
            float4 v = *(const float4*)(wbuf + gidx * 16);
            *(float4*)(wdst + gidx * 4) = v;
        }
    }
}

// ---------------------------------------------------------------------------
extern "C" void kernel_launch(void* const* d_in, const int* in_sizes, int n_in,
                              void* d_out, int out_size, void* d_ws, size_t ws_size,
                              hipStream_t stream) {
    const float* activations = (const float*)d_in[0];
    const float* filt        = (const float*)d_in[1];
    float* out               = (float*)d_out;
    float* ws                = (float*)d_ws;   // g + B-fragment arrays (~17 KB)

    hipLaunchKernelGGL(compute_inverse_filter, dim3(1), dim3(BT), 0, stream,
                       filt, ws);

    const long long total = (long long)in_sizes[0];
    const long long rows  = total / SCOPE;          // 524288
    const int blocks      = (int)(rows / RPB);      // 8192, exact

    hipLaunchKernelGGL(circ_conv_kernel, dim3(blocks), dim3(BT), 0,
                       stream, activations, ws, out);
}